// Round 6
// baseline (417.762 us; speedup 1.0000x reference)
//
#include <hip/hip_runtime.h>

// ---------------------------------------------------------------------------
// MultiHeadAttention (softmax over QUERY axis) — MI355X / gfx950, bf16 MFMA.
// B=4, S=2048, D=1024, H=16, Dk=64. Inputs/outputs fp32.
// attn[i,j] = exp(s_ij)/L_j, L_j = sum_i exp(s_ij)   (column softmax)
//
// ws (64 MiB): Qb@0 | Kb@16MiB | Vb@32MiB | Xb@48MiB  (bf16 [B,H,S,Dk]/[B,S,D])
// d_out scratch until final GEMM: Lg@+0 (512KiB) | WtQ/WtK/WtV bf16 @+1MiB.
// WtO transposed into ws@0 (Qb region, dead after attn_pv).
//
// ROUND-11: gemm128 BK 64->32, dbuf retained (LDS 64->32 KB), launch_bounds
// (256,4): 2 -> 4 blocks/CU (8 -> 16 waves/CU).  Round-5's BK=64 was the
// m132 trap (64KB LDS halves occupancy; TLP is what hides staging here).
// fp32-A staging cvts to bf16 at load time (xv regs) to stay <=128 VGPR.
// Swizzle geometry = round-2/3-verified 32-elem-row scheme (c ^ (row&3)).
// attn_pv / colsum / wtrans unchanged from round-5 (verified).
// ---------------------------------------------------------------------------

#define B_   4
#define S_   2048
#define D_   1024
#define H_   16
#define DK_  64
#define BH_  64
#define SC2_    0.18033688f   // 0.125 * log2(e), folded into Q projection

typedef __bf16 bf16x2 __attribute__((ext_vector_type(2)));
typedef __bf16 bf16x4 __attribute__((ext_vector_type(4)));
typedef __bf16 bf16x8 __attribute__((ext_vector_type(8)));
typedef float  f32x4  __attribute__((ext_vector_type(4)));
typedef unsigned int u32;

#define MFMA16(a,b,c) __builtin_amdgcn_mfma_f32_16x16x32_bf16((a),(b),(c),0,0,0)

__device__ __forceinline__ bf16x8 ld8(const __bf16* p){ return *(const bf16x8*)p; }

// async global->LDS, 16B per lane; LDS dest = wave-uniform base + lane*16
__device__ __forceinline__ void gll16(const __bf16* g, __bf16* l) {
    __builtin_amdgcn_global_load_lds(
        (const __attribute__((address_space(1))) u32*)g,
        (__attribute__((address_space(3))) u32*)l, 16, 0, 0);
}

// ---------------------------------------------------------------------------
// wtrans3: W [k][n] fp32 -> Wt [n][k] bf16, 3 matrices (blockIdx.z selects).
// 64x64 tile via LDS [64][80] (stride 160B: 16B-aligned, 2-lanes/bank).
// ---------------------------------------------------------------------------
__global__ __launch_bounds__(256) void wtrans3(
    const float* __restrict__ W0, const float* __restrict__ W1,
    const float* __restrict__ W2, __bf16* __restrict__ Wt)
{
    __shared__ __align__(16) __bf16 Ls[64][80];
    const int t = threadIdx.x;
    const int k0 = blockIdx.x * 64, n0 = blockIdx.y * 64, z = blockIdx.z;
    const float* W = (z == 0) ? W0 : ((z == 1) ? W1 : W2);
    __bf16* out = Wt + (size_t)z * D_ * D_;

#pragma unroll
    for (int p = 0; p < 4; ++p) {               // 1024 tasks: 64 k x 16 n-quads
        int id = p*256 + t;
        int k = id >> 4, nq = id & 15;
        f32x4 v = *(const f32x4*)&W[(size_t)(k0 + k)*D_ + n0 + nq*4];
#pragma unroll
        for (int u = 0; u < 4; ++u) Ls[nq*4 + u][k] = (__bf16)v[u];
    }
    __syncthreads();
#pragma unroll
    for (int p = 0; p < 2; ++p) {               // 512 tasks: 64 n x 8 chunks
        int id = p*256 + t;
        int n = id >> 3, c = id & 7;
        *(bf16x8*)&out[(size_t)(n0 + n)*D_ + k0 + c*8] =
            *(const bf16x8*)&Ls[n][c*8];
    }
}

// ---------------------------------------------------------------------------
// GEMM  C[m][n] = (sum_k A[m][k]*Wt[n][k] + bias[n]) * scale   (Wt = W^T bf16)
//   128x128 tile, BK=32, DOUBLE-BUFFERED LDS (32 KB), one barrier/iter (32).
//   4 waves (2x2, 64x64 each), 16 MFMA/iter.  launch_bounds(256,4) ->
//   4 blocks/CU, 16 waves/CU.  1D grid 512: m = gid&63 (XCD A-panel group).
//   Row = 32 elem (4 chunks); swizzle: phys chunk c holds logical c^(row&3);
//   read at phys fq^(row&3).  bf16-A/B staged via gll16 (pre-swizzled src);
//   fp32-A: reg-load + cvt at iter top, b128 LDS write AFTER the MFMAs (T14).
//   MODE 0: C fp32 [8192][1024]; MODE 1: C bf16 scatter [B,H,S,Dk].
//   QS: multiply output by SC2_ (Q projection only).
// ---------------------------------------------------------------------------
template<int ABF16, int MODE, int QS>
__global__ __launch_bounds__(256, 4) void gemm128(
    const void* __restrict__ Ap, const __bf16* __restrict__ Wt,
    const float* __restrict__ bias, void* __restrict__ C)
{
    __shared__ __align__(16) __bf16 As[2][128*32];   // 8 KB x2
    __shared__ __align__(16) __bf16 Bs[2][128*32];   // 8 KB x2

    const int t = threadIdx.x, lane = t & 63, w = t >> 6;
    const int wm = w >> 1, wn = w & 1;
    const int fr = lane & 15, fq = lane >> 4;
    const int gid = blockIdx.x;
    const int m0 = (gid & 63) * 128, n0 = (gid >> 6) * 128;

    const __bf16* Ab = (const __bf16*)Ap;
    const float*  Af = (const float*)Ap;

    f32x4 acc[4][4];
#pragma unroll
    for (int i = 0; i < 4; ++i)
#pragma unroll
        for (int j = 0; j < 4; ++j) acc[i][j] = (f32x4){0.f,0.f,0.f,0.f};

    // staging: 512 chunks of 16B; id = p*256+t (p<2); row = id>>2; phys chunk
    // c = id&3 holds logical l = c^(row&3); LDS linear at id*16B.
#define STAGE_B32(kk, bsel)                                                   \
    _Pragma("unroll")                                                         \
    for (int p = 0; p < 2; ++p) {                                             \
        int id = p*256 + t;                                                   \
        int n = id >> 2, l = (id & 3) ^ (n & 3);                              \
        gll16(&Wt[(size_t)(n0 + n)*D_ + (kk) + l*8],                          \
              &Bs[bsel][(size_t)(p*256 + (t & ~63))*8]);                      \
    }

#define STAGE_A32(kk, bsel)                                                   \
    _Pragma("unroll")                                                         \
    for (int p = 0; p < 2; ++p) {                                             \
        int id = p*256 + t;                                                   \
        int row = id >> 2, l = (id & 3) ^ (row & 3);                          \
        gll16(&Ab[(size_t)(m0 + row)*D_ + (kk) + l*8],                        \
              &As[bsel][(size_t)(p*256 + (t & ~63))*8]);                      \
    }

#define LOADCVT_A32(kk, xv)                                                   \
    _Pragma("unroll")                                                         \
    for (int p = 0; p < 2; ++p) {                                             \
        int id = p*256 + t;                                                   \
        int row = id >> 2, l = (id & 3) ^ (row & 3);                          \
        const float* ap = &Af[(size_t)(m0 + row)*D_ + (kk) + l*8];            \
        f32x4 x0 = *(const f32x4*)ap;                                         \
        f32x4 x1 = *(const f32x4*)(ap + 4);                                   \
        xv[p] = (bf16x8){ (__bf16)x0[0], (__bf16)x0[1], (__bf16)x0[2],        \
                          (__bf16)x0[3], (__bf16)x1[0], (__bf16)x1[1],        \
                          (__bf16)x1[2], (__bf16)x1[3] };                     \
    }

#define WRITE_A32(xv, bsel)                                                   \
    _Pragma("unroll")                                                         \
    for (int p = 0; p < 2; ++p)                                               \
        *(bf16x8*)&As[bsel][(size_t)(p*256 + t)*8] = xv[p];

    // prologue: stage k-tile 0 into buffer 0
    if (ABF16) {
        STAGE_A32(0, 0)
    } else {
        bf16x8 xv0[2];
        LOADCVT_A32(0, xv0)
        WRITE_A32(xv0, 0)
    }
    STAGE_B32(0, 0)
    __syncthreads();

    for (int kk = 0; kk < D_; kk += 32) {
        const int cur = (kk >> 5) & 1;
        const bool more = (kk + 32) < D_;

        bf16x8 xv[2];
        if (more) {
            if (ABF16) {
                STAGE_A32(kk + 32, cur ^ 1)
            } else {
                LOADCVT_A32(kk + 32, xv)
            }
            STAGE_B32(kk + 32, cur ^ 1)
        }

        bf16x8 af[4], bfr[4];
#pragma unroll
        for (int mt = 0; mt < 4; ++mt) {
            int row = wm*64 + mt*16 + fr;
            af[mt] = ld8(&As[cur][row*32 + 8*(fq ^ (row & 3))]);
        }
#pragma unroll
        for (int nt = 0; nt < 4; ++nt) {
            int n = wn*64 + nt*16 + fr;
            bfr[nt] = ld8(&Bs[cur][n*32 + 8*(fq ^ (n & 3))]);
        }
#pragma unroll
        for (int mt = 0; mt < 4; ++mt)
#pragma unroll
            for (int nt = 0; nt < 4; ++nt)
                acc[mt][nt] = MFMA16(af[mt], bfr[nt], acc[mt][nt]);

        if (more && !ABF16) {
            WRITE_A32(xv, cur ^ 1)
        }
        __syncthreads();
    }
#undef STAGE_B32
#undef STAGE_A32
#undef LOADCVT_A32
#undef WRITE_A32

#pragma unroll
    for (int mt = 0; mt < 4; ++mt)
#pragma unroll
        for (int nt = 0; nt < 4; ++nt) {
            int colg = n0 + wn*64 + nt*16 + fr;
            float bv = bias[colg];
#pragma unroll
            for (int r = 0; r < 4; ++r) {
                int rowg = m0 + wm*64 + mt*16 + fq*4 + r;
                float o = acc[mt][nt][r] + bv;
                if (QS) o *= SC2_;
                if (MODE == 0) {
                    ((float*)C)[(size_t)rowg*D_ + colg] = o;
                } else {
                    int b = rowg >> 11, sp = rowg & (S_-1);
                    int h = colg >> 6, dk = colg & 63;
                    ((__bf16*)C)[(((size_t)(b*H_ + h))*S_ + sp)*DK_ + dk] = (__bf16)o;
                }
            }
        }
}

// ---------------------------------------------------------------------------
// Column-softmax log-sums: Lg[bh][j] = -log2( sum_i exp2(s_ij) ).
//   1024 blocks (1D, bh = gid&63 -> XCD-local Q), 4 waves x 32 j each.
//   K-frags loop-invariant in regs; i-step 64, Qs dbuf via gll16 prefetch
//   (pre-swizzled source, i&7 chunk XOR), ONE barrier per step.
// ---------------------------------------------------------------------------
__global__ __launch_bounds__(256) void colsum_rcp(
    const __bf16* __restrict__ Q, const __bf16* __restrict__ K,
    float* __restrict__ Lg)
{
    __shared__ __align__(16) __bf16 Qs[2][64*64];   // 16 KB
    const int t = threadIdx.x, lane = t & 63, w = t >> 6;
    const int fr = lane & 15, fq = lane >> 4;
    const int gid = blockIdx.x;
    const int bh = gid & 63;
    const int jw = (gid >> 6)*128 + w*32;
    const __bf16* Qb = Q + (size_t)bh*S_*DK_;
    const __bf16* Kb = K + (size_t)bh*S_*DK_;

    bf16x8 kh[2][2];
#pragma unroll
    for (int jt = 0; jt < 2; ++jt) {
        const __bf16* kr = &Kb[(size_t)(jw + jt*16 + fr)*DK_];
        kh[jt][0] = ld8(kr + fq*8);
        kh[jt][1] = ld8(kr + 32 + fq*8);
    }

    float accl[2][4] = {};

    // prologue: stage Qs[0] (rows 0..63), pre-swizzled source
#pragma unroll
    for (int p = 0; p < 2; ++p) {
        int c = p*256 + t;
        int i = c >> 3, l = (c & 7) ^ (i & 7);
        gll16(&Qb[(size_t)i*DK_ + l*8], &Qs[0][(size_t)(p*256 + (t & ~63))*8]);
    }
    __syncthreads();

    for (int i0 = 0; i0 < S_; i0 += 64) {
        const int cur = (i0 >> 6) & 1;
        if (i0 + 64 < S_) {
#pragma unroll
            for (int p = 0; p < 2; ++p) {
                int c = p*256 + t;
                int i = c >> 3, l = (c & 7) ^ (i & 7);
                gll16(&Qb[(size_t)(i0 + 64 + i)*DK_ + l*8],
                      &Qs[cur ^ 1][(size_t)(p*256 + (t & ~63))*8]);
            }
        }
#pragma unroll
        for (int it = 0; it < 4; ++it) {
            int i = it*16 + fr;
            bf16x8 q0 = ld8(&Qs[cur][i*64 + 8*(fq ^ (i & 7))]);
            bf16x8 q1 = ld8(&Qs[cur][i*64 + 8*((4 + fq) ^ (i & 7))]);
#pragma unroll
            for (int jt = 0; jt < 2; ++jt) {
                f32x4 s = MFMA16(kh[jt][0], q0, ((f32x4){0.f,0.f,0.f,0.f}));
                s = MFMA16(kh[jt][1], q1, s);
#pragma unroll
                for (int r = 0; r < 4; ++r)
                    accl[jt][r] += __builtin_amdgcn_exp2f(s[r]);
            }
        }
        __syncthreads();
    }
#pragma unroll
    for (int jt = 0; jt < 2; ++jt)
#pragma unroll
        for (int r = 0; r < 4; ++r) {
            accl[jt][r] += __shfl_xor(accl[jt][r], 1, 64);
            accl[jt][r] += __shfl_xor(accl[jt][r], 2, 64);
            accl[jt][r] += __shfl_xor(accl[jt][r], 4, 64);
            accl[jt][r] += __shfl_xor(accl[jt][r], 8, 64);
        }
    if (fr == 0) {
#pragma unroll
        for (int jt = 0; jt < 2; ++jt)
#pragma unroll
            for (int r = 0; r < 4; ++r)
                Lg[(size_t)bh*S_ + jw + jt*16 + fq*4 + r] =
                    -__log2f(accl[jt][r]);
    }
}

// ---------------------------------------------------------------------------
// Pass 2: X[i,:] = sum_j exp2(s_ij + Lg_j) * V[j,:]   (s pre-scaled by SC2)
// Lg folded into the score-MFMA C operand (C rows = j).  512 thr / 8 waves,
// 256 i, j-step 64, 1 barrier/step, K dbuf via gll16 pre-swizzled, V
// transpose-staged swizzled, wave-private P, setprio around PV MFMAs.
// 1D grid 512, bh = gid&63 -> all i-tiles of a (b,h) on one XCD.
// ---------------------------------------------------------------------------
__global__ __launch_bounds__(512, 4) void attn_pv(
    const __bf16* __restrict__ Q, const __bf16* __restrict__ K,
    const __bf16* __restrict__ V, const float* __restrict__ Lg,
    __bf16* __restrict__ X)
{
    __shared__ __align__(16) __bf16 Ks[2][64*64];   // 16 KB
    __shared__ __align__(16) __bf16 Vs[2][64*64];   // 16 KB
    __shared__ __align__(16) __bf16 Pl[8][32*64];   // 32 KB

    const int t = threadIdx.x, lane = t & 63, w = t >> 6;
    const int fr = lane & 15, fq = lane >> 4;
    const int gid = blockIdx.x;
    const int bh = gid & 63;
    const int iw = (gid >> 6)*256 + w*32;           // wave's i base
    const __bf16* Qb = Q + (size_t)bh*S_*DK_;
    const __bf16* Kb = K + (size_t)bh*S_*DK_;
    const __bf16* Vb = V + (size_t)bh*S_*DK_;
    const float*  Rb = Lg + (size_t)bh*S_;

    bf16x8 qf[2][2];
#pragma unroll
    for (int it = 0; it < 2; ++it)
#pragma unroll
        for (int kf = 0; kf < 2; ++kf)
            qf[it][kf] = ld8(&Qb[(size_t)(iw + it*16 + fr)*DK_ + kf*32 + fq*8]);

    const int dq = t & 15, jp = t >> 4;
    const int krow = t >> 3;
    const int kchk = (t & 7) ^ (krow & 7);

    f32x4 acc[2][4];
#pragma unroll
    for (int it = 0; it < 2; ++it)
#pragma unroll
        for (int dt = 0; dt < 4; ++dt) acc[it][dt] = (f32x4){0.f,0.f,0.f,0.f};

    gll16(&Kb[(size_t)krow*DK_ + kchk*8], &Ks[0][(t & ~63)*8]);
    __syncthreads();

    for (int jg = 0; jg < S_; jg += 64) {
        const int cur = (jg >> 6) & 1;

        bf16x4 v0 = *(const bf16x4*)&Vb[(size_t)(jg + 2*jp    )*DK_ + dq*4];
        bf16x4 v1 = *(const bf16x4*)&Vb[(size_t)(jg + 2*jp + 1)*DK_ + dq*4];
        f32x4 lg[4];
#pragma unroll
        for (int jt = 0; jt < 4; ++jt)
            lg[jt] = *(const f32x4*)&Rb[jg + jt*16 + fq*4];
        if (jg + 64 < S_)
            gll16(&Kb[(size_t)(jg + 64 + krow)*DK_ + kchk*8],
                  &Ks[cur ^ 1][(t & ~63)*8]);

#pragma unroll
        for (int jt = 0; jt < 4; ++jt) {
            const __bf16* kb = &Ks[cur][(jt*16 + fr)*64];
            bf16x8 af0 = ld8(kb + ((fq    ) ^ (fr & 7))*8);
            bf16x8 af1 = ld8(kb + ((fq + 4) ^ (fr & 7))*8);
#pragma unroll
            for (int it = 0; it < 2; ++it) {
                f32x4 s = MFMA16(af0, qf[it][0], lg[jt]);   // C-init = -log2 L
                s = MFMA16(af1, qf[it][1], s);
                bf16x4 pv;
#pragma unroll
                for (int r = 0; r < 4; ++r)
                    pv[r] = (__bf16)__builtin_amdgcn_exp2f(s[r]);
                int il = it*16 + fr;
                *(bf16x4*)&Pl[w][il*64 + (((jt*4 + fq) ^ (2*(fr & 7))))*4] = pv;
            }
        }

#pragma unroll
        for (int u = 0; u < 4; ++u) {
            int d = dq*4 + u;
            int f = (d ^ dq) & 7;
            *(bf16x2*)&Vs[cur][d*64 + (((jp >> 2) ^ f))*8 + (jp & 3)*2] =
                (bf16x2){ v0[u], v1[u] };
        }
        __syncthreads();

        __builtin_amdgcn_s_setprio(1);
#pragma unroll
        for (int kh = 0; kh < 2; ++kh) {
            bf16x8 pa0 = ld8(&Pl[w][(     fr)*64 + (((fq + 4*kh) ^ (fr & 7)))*8]);
            bf16x8 pa1 = ld8(&Pl[w][(16 + fr)*64 + (((fq + 4*kh) ^ (fr & 7)))*8]);
#pragma unroll
            for (int dt = 0; dt < 4; ++dt) {
                int d = dt*16 + fr;
                int f = (d ^ (d >> 2)) & 7;
                bf16x8 vb = ld8(&Vs[cur][d*64 + (((kh*4 + fq) ^ f))*8]);
                acc[0][dt] = MFMA16(pa0, vb, acc[0][dt]);
                acc[1][dt] = MFMA16(pa1, vb, acc[1][dt]);
            }
        }
        __builtin_amdgcn_s_setprio(0);
    }

    const int b = bh >> 4, h = bh & 15;
#pragma unroll
    for (int it = 0; it < 2; ++it)
#pragma unroll
        for (int dt = 0; dt < 4; ++dt)
#pragma unroll
            for (int r = 0; r < 4; ++r) {
                int i = iw + it*16 + fq*4 + r;
                X[((size_t)b*S_ + i)*D_ + h*DK_ + dt*16 + fr] =
                    (__bf16)acc[it][dt][r];
            }
}

// ---------------------------------------------------------------------------
// Host launcher
// ---------------------------------------------------------------------------
extern "C" void kernel_launch(void* const* d_in, const int* in_sizes, int n_in,
                              void* d_out, int out_size, void* d_ws, size_t ws_size,
                              hipStream_t stream)
{
    const float* query = (const float*)d_in[0];
    const float* key   = (const float*)d_in[1];
    const float* value = (const float*)d_in[2];
    const float* Wq = (const float*)d_in[3];  const float* bq = (const float*)d_in[4];
    const float* Wk = (const float*)d_in[5];  const float* bk = (const float*)d_in[6];
    const float* Wv = (const float*)d_in[7];  const float* bv = (const float*)d_in[8];
    const float* Wo = (const float*)d_in[9];  const float* bo = (const float*)d_in[10];

    char* ws = (char*)d_ws;
    char* dob = (char*)d_out;
    const size_t MiB = 1024 * 1024;
    __bf16* Qb = (__bf16*)(ws);              // [B,H,S,Dk] 16 MiB
    __bf16* Kb = (__bf16*)(ws + 16 * MiB);
    __bf16* Vb = (__bf16*)(ws + 32 * MiB);
    __bf16* Xb = (__bf16*)(ws + 48 * MiB);   // [B,S,D]
    float*  Lgb = (float*)d_out;             // 512 KiB @ d_out+0 (-log2 L)
    __bf16* Wt3 = (__bf16*)(dob + 1 * MiB);  // WtQ|WtK|WtV, 2 MiB each
    __bf16* WtO = (__bf16*)(ws);             // Qb region, reused after attn_pv

    // weights -> W^T bf16 (scratch in d_out; dead until final GEMM)
    wtrans3<<<dim3(16,16,3), 256, 0, stream>>>(Wq, Wk, Wv, Wt3);

    // projections (Q scaled by SC2_ in epilogue); 1D XCD-aware grid
    gemm128<0,1,1><<<512, 256, 0, stream>>>(query, Wt3,                  bq, Qb);
    gemm128<0,1,0><<<512, 256, 0, stream>>>(key,   Wt3 + (size_t)D_*D_,  bk, Kb);
    gemm128<0,1,0><<<512, 256, 0, stream>>>(value, Wt3 + (size_t)2*D_*D_,bv, Vb);

    colsum_rcp<<<1024, 256, 0, stream>>>(Qb, Kb, Lgb);

    attn_pv<<<512, 512, 0, stream>>>(Qb, Kb, Vb, Lgb, Xb);

    // Wo^T into Qb region (dead now); then final GEMM reads it from ws
    wtrans3<<<dim3(16,16,1), 256, 0, stream>>>(Wo, Wo, Wo, WtO);

    gemm128<1,0,0><<<512, 256, 0, stream>>>(Xb, WtO, bo, d_out);
}

// Round 7
// 382.364 us; speedup vs baseline: 1.0926x; 1.0926x over previous
//
#include <hip/hip_runtime.h>

// ---------------------------------------------------------------------------
// MultiHeadAttention (softmax over QUERY axis) — MI355X / gfx950, bf16 MFMA.
// B=4, S=2048, D=1024, H=16, Dk=64. Inputs/outputs fp32.
// attn[i,j] = exp(s_ij)/L_j, L_j = sum_i exp(s_ij)   (column softmax)
//
// ws (64 MiB): Qb@0 | Kb@16MiB | Vb@32MiB | Xb@48MiB  (bf16 [B,H,S,Dk]/[B,S,D])
// d_out scratch until final GEMM: Lg@+0 (512KiB) | WtQ/WtK/WtV bf16 @+1MiB.
// WtO transposed into ws@0 (Qb region, dead after attn_pv).
//
// ROUND-12: (a) gemm body reverted to the round-5 (measured-best) BK=64
// double-buffered single-barrier schedule; round-6's BK=32+(256,4) regressed
// (drain separation halved + 128-VGPR clamp).  QS template -> runtime scale.
// (b) The 3 projections batched into ONE 1536-block launch (z = gid>>9):
// removes 2 launch gaps + 2 tail drains, and surfaces GEMM counters in the
// rocprof top-5 for the first time (go/no-go gate for an 8-phase port).
// attn_pv / colsum / wtrans unchanged (verified at 80 us / ~50 us).
// ---------------------------------------------------------------------------

#define B_   4
#define S_   2048
#define D_   1024
#define H_   16
#define DK_  64
#define BH_  64
#define SC2_    0.18033688f   // 0.125 * log2(e), folded into Q projection

typedef __bf16 bf16x2 __attribute__((ext_vector_type(2)));
typedef __bf16 bf16x4 __attribute__((ext_vector_type(4)));
typedef __bf16 bf16x8 __attribute__((ext_vector_type(8)));
typedef float  f32x4  __attribute__((ext_vector_type(4)));
typedef unsigned int u32;

#define MFMA16(a,b,c) __builtin_amdgcn_mfma_f32_16x16x32_bf16((a),(b),(c),0,0,0)

__device__ __forceinline__ bf16x8 ld8(const __bf16* p){ return *(const bf16x8*)p; }

// async global->LDS, 16B per lane; LDS dest = wave-uniform base + lane*16
__device__ __forceinline__ void gll16(const __bf16* g, __bf16* l) {
    __builtin_amdgcn_global_load_lds(
        (const __attribute__((address_space(1))) u32*)g,
        (__attribute__((address_space(3))) u32*)l, 16, 0, 0);
}

// ---------------------------------------------------------------------------
// wtrans3: W [k][n] fp32 -> Wt [n][k] bf16, 3 matrices (blockIdx.z selects).
// 64x64 tile via LDS [64][80] (stride 160B: 16B-aligned, 2-lanes/bank).
// ---------------------------------------------------------------------------
__global__ __launch_bounds__(256) void wtrans3(
    const float* __restrict__ W0, const float* __restrict__ W1,
    const float* __restrict__ W2, __bf16* __restrict__ Wt)
{
    __shared__ __align__(16) __bf16 Ls[64][80];
    const int t = threadIdx.x;
    const int k0 = blockIdx.x * 64, n0 = blockIdx.y * 64, z = blockIdx.z;
    const float* W = (z == 0) ? W0 : ((z == 1) ? W1 : W2);
    __bf16* out = Wt + (size_t)z * D_ * D_;

#pragma unroll
    for (int p = 0; p < 4; ++p) {               // 1024 tasks: 64 k x 16 n-quads
        int id = p*256 + t;
        int k = id >> 4, nq = id & 15;
        f32x4 v = *(const f32x4*)&W[(size_t)(k0 + k)*D_ + n0 + nq*4];
#pragma unroll
        for (int u = 0; u < 4; ++u) Ls[nq*4 + u][k] = (__bf16)v[u];
    }
    __syncthreads();
#pragma unroll
    for (int p = 0; p < 2; ++p) {               // 512 tasks: 64 n x 8 chunks
        int id = p*256 + t;
        int n = id >> 3, c = id & 7;
        *(bf16x8*)&out[(size_t)(n0 + n)*D_ + k0 + c*8] =
            *(const bf16x8*)&Ls[n][c*8];
    }
}

// ---------------------------------------------------------------------------
// GEMM body  C[m][n] = (sum_k A[m][k]*Wt[n][k] + bias[n]) * scale
//   (round-5 measured-best schedule)
//   128x128 tile, BK=64, DOUBLE-BUFFERED LDS (64 KB), one barrier per K-iter.
//   4 waves (2x2, 64x64 each), 32 MFMA/iter.
//   Row stride 64 elem (128 B): chunk swizzle c^(row&7).  bf16-A/B staged via
//   gll16 (pre-swizzled src); fp32-A: reg-load at iter top, cvt + b128 LDS
//   write AFTER the MFMAs (T14).
//   MODE 0: C fp32 [8192][1024]; MODE 1: C bf16 scatter [B,H,S,Dk].
// ---------------------------------------------------------------------------
template<int ABF16, int MODE>
__device__ __forceinline__ void gemm_body(
    const void* __restrict__ Ap, const __bf16* __restrict__ Wt,
    const float* __restrict__ bias, void* __restrict__ C,
    float scale, int m0, int n0)
{
    __shared__ __align__(16) __bf16 As[2][128*64];   // 16 KB x2
    __shared__ __align__(16) __bf16 Bs[2][128*64];   // 16 KB x2

    const int t = threadIdx.x, lane = t & 63, w = t >> 6;
    const int wm = w >> 1, wn = w & 1;
    const int fr = lane & 15, fq = lane >> 4;

    const __bf16* Ab = (const __bf16*)Ap;
    const float*  Af = (const float*)Ap;

    f32x4 acc[4][4];
#pragma unroll
    for (int i = 0; i < 4; ++i)
#pragma unroll
        for (int j = 0; j < 4; ++j) acc[i][j] = (f32x4){0.f,0.f,0.f,0.f};

    // staging task: idx = p*256+t (0..1023), row = idx>>3, phys chunk = idx&7,
    // logical chunk l = (idx&7)^(row&7); LDS offset = idx*8 (linear).
#define STAGE_B(kk, bsel)                                                     \
    _Pragma("unroll")                                                         \
    for (int p = 0; p < 4; ++p) {                                             \
        int idx = p*256 + t;                                                  \
        int n = idx >> 3, l = (idx & 7) ^ (n & 7);                            \
        gll16(&Wt[(size_t)(n0 + n)*D_ + (kk) + l*8],                          \
              &Bs[bsel][(size_t)(p*256 + (t & ~63))*8]);                      \
    }

#define STAGE_A_BF(kk, bsel)                                                  \
    _Pragma("unroll")                                                         \
    for (int p = 0; p < 4; ++p) {                                             \
        int idx = p*256 + t;                                                  \
        int row = idx >> 3, l = (idx & 7) ^ (row & 7);                        \
        gll16(&Ab[(size_t)(m0 + row)*D_ + (kk) + l*8],                        \
              &As[bsel][(size_t)(p*256 + (t & ~63))*8]);                      \
    }

#define LOAD_A_F32(kk, xa)                                                    \
    _Pragma("unroll")                                                         \
    for (int p = 0; p < 4; ++p) {                                             \
        int idx = p*256 + t;                                                  \
        int row = idx >> 3, l = (idx & 7) ^ (row & 7);                        \
        const float* ap = &Af[(size_t)(m0 + row)*D_ + (kk) + l*8];            \
        xa[2*p]   = *(const f32x4*)ap;                                        \
        xa[2*p+1] = *(const f32x4*)(ap + 4);                                  \
    }

#define WRITE_A_F32(xa, bsel)                                                 \
    _Pragma("unroll")                                                         \
    for (int p = 0; p < 4; ++p) {                                             \
        f32x4 x0 = xa[2*p], x1 = xa[2*p+1];                                   \
        bf16x8 v = { (__bf16)x0[0], (__bf16)x0[1], (__bf16)x0[2],             \
                     (__bf16)x0[3], (__bf16)x1[0], (__bf16)x1[1],             \
                     (__bf16)x1[2], (__bf16)x1[3] };                          \
        *(bf16x8*)&As[bsel][(size_t)(p*256 + t)*8] = v;                       \
    }

    // prologue: stage k-tile 0 into buffer 0
    if (ABF16) {
        STAGE_A_BF(0, 0)
    } else {
        f32x4 xa[8];
        LOAD_A_F32(0, xa)
        WRITE_A_F32(xa, 0)
    }
    STAGE_B(0, 0)
    __syncthreads();

    for (int kk = 0; kk < D_; kk += 64) {
        const int cur = (kk >> 6) & 1;
        const bool more = (kk + 64) < D_;

        f32x4 xa[8];
        if (more) {
            if (ABF16) {
                STAGE_A_BF(kk + 64, cur ^ 1)
            } else {
                LOAD_A_F32(kk + 64, xa)
            }
            STAGE_B(kk + 64, cur ^ 1)
        }

        // compute 2 k-halves from buffer cur
#pragma unroll
        for (int kh = 0; kh < 2; ++kh) {
            bf16x8 af[4], bfr[4];
#pragma unroll
            for (int mt = 0; mt < 4; ++mt) {
                int row = wm*64 + mt*16 + fr;
                af[mt] = ld8(&As[cur][row*64 + 8*((kh*4 + fq) ^ (row & 7))]);
            }
#pragma unroll
            for (int nt = 0; nt < 4; ++nt) {
                int n = wn*64 + nt*16 + fr;
                bfr[nt] = ld8(&Bs[cur][n*64 + 8*((kh*4 + fq) ^ (n & 7))]);
            }
#pragma unroll
            for (int mt = 0; mt < 4; ++mt)
#pragma unroll
                for (int nt = 0; nt < 4; ++nt)
                    acc[mt][nt] = MFMA16(af[mt], bfr[nt], acc[mt][nt]);
        }

        if (more && !ABF16) {
            WRITE_A_F32(xa, cur ^ 1)
        }
        __syncthreads();
    }
#undef STAGE_B
#undef STAGE_A_BF
#undef LOAD_A_F32
#undef WRITE_A_F32

#pragma unroll
    for (int mt = 0; mt < 4; ++mt)
#pragma unroll
        for (int nt = 0; nt < 4; ++nt) {
            int colg = n0 + wn*64 + nt*16 + fr;
            float bv = bias[colg];
#pragma unroll
            for (int r = 0; r < 4; ++r) {
                int rowg = m0 + wm*64 + mt*16 + fq*4 + r;
                float o = (acc[mt][nt][r] + bv) * scale;
                if (MODE == 0) {
                    ((float*)C)[(size_t)rowg*D_ + colg] = o;
                } else {
                    int b = rowg >> 11, sp = rowg & (S_-1);
                    int h = colg >> 6, dk = colg & 63;
                    ((__bf16*)C)[(((size_t)(b*H_ + h))*S_ + sp)*DK_ + dk] = (__bf16)o;
                }
            }
        }
}

// single-GEMM wrapper (final output GEMM); 1D grid 512: m = gid&63
template<int ABF16, int MODE>
__global__ __launch_bounds__(256) void gemm128(
    const void* __restrict__ Ap, const __bf16* __restrict__ Wt,
    const float* __restrict__ bias, void* __restrict__ C, float scale)
{
    const int gid = blockIdx.x;
    gemm_body<ABF16, MODE>(Ap, Wt, bias, C, scale,
                           (gid & 63) * 128, ((gid >> 6) & 7) * 128);
}

// batched Q/K/V projection: 1536 blocks, z = gid>>9 selects the sub-GEMM.
// (gid&511) keeps the XCD m-grouping (512 % 64 == 0).
__global__ __launch_bounds__(256) void gemm_proj3(
    const float* __restrict__ q, const float* __restrict__ k,
    const float* __restrict__ v, const __bf16* __restrict__ Wt3,
    const float* __restrict__ bq, const float* __restrict__ bk,
    const float* __restrict__ bv,
    __bf16* __restrict__ Qb, __bf16* __restrict__ Kb, __bf16* __restrict__ Vb)
{
    const int gid = blockIdx.x;
    const int z = gid >> 9, inner = gid & 511;
    const float*  A    = (z == 0) ? q  : ((z == 1) ? k  : v);
    const __bf16* Wt   = Wt3 + (size_t)z * D_ * D_;
    const float*  bias = (z == 0) ? bq : ((z == 1) ? bk : bv);
    __bf16*       C    = (z == 0) ? Qb : ((z == 1) ? Kb : Vb);
    const float scale  = (z == 0) ? SC2_ : 1.0f;
    gemm_body<0, 1>(A, Wt, bias, C, scale,
                    (inner & 63) * 128, (inner >> 6) * 128);
}

// ---------------------------------------------------------------------------
// Column-softmax log-sums: Lg[bh][j] = -log2( sum_i exp2(s_ij) ).
//   1024 blocks (1D, bh = gid&63 -> XCD-local Q), 4 waves x 32 j each.
//   K-frags loop-invariant in regs; i-step 64, Qs dbuf via gll16 prefetch
//   (pre-swizzled source, i&7 chunk XOR), ONE barrier per step.
// ---------------------------------------------------------------------------
__global__ __launch_bounds__(256) void colsum_rcp(
    const __bf16* __restrict__ Q, const __bf16* __restrict__ K,
    float* __restrict__ Lg)
{
    __shared__ __align__(16) __bf16 Qs[2][64*64];   // 16 KB
    const int t = threadIdx.x, lane = t & 63, w = t >> 6;
    const int fr = lane & 15, fq = lane >> 4;
    const int gid = blockIdx.x;
    const int bh = gid & 63;
    const int jw = (gid >> 6)*128 + w*32;
    const __bf16* Qb = Q + (size_t)bh*S_*DK_;
    const __bf16* Kb = K + (size_t)bh*S_*DK_;

    bf16x8 kh[2][2];
#pragma unroll
    for (int jt = 0; jt < 2; ++jt) {
        const __bf16* kr = &Kb[(size_t)(jw + jt*16 + fr)*DK_];
        kh[jt][0] = ld8(kr + fq*8);
        kh[jt][1] = ld8(kr + 32 + fq*8);
    }

    float accl[2][4] = {};

    // prologue: stage Qs[0] (rows 0..63), pre-swizzled source
#pragma unroll
    for (int p = 0; p < 2; ++p) {
        int c = p*256 + t;
        int i = c >> 3, l = (c & 7) ^ (i & 7);
        gll16(&Qb[(size_t)i*DK_ + l*8], &Qs[0][(size_t)(p*256 + (t & ~63))*8]);
    }
    __syncthreads();

    for (int i0 = 0; i0 < S_; i0 += 64) {
        const int cur = (i0 >> 6) & 1;
        if (i0 + 64 < S_) {
#pragma unroll
            for (int p = 0; p < 2; ++p) {
                int c = p*256 + t;
                int i = c >> 3, l = (c & 7) ^ (i & 7);
                gll16(&Qb[(size_t)(i0 + 64 + i)*DK_ + l*8],
                      &Qs[cur ^ 1][(size_t)(p*256 + (t & ~63))*8]);
            }
        }
#pragma unroll
        for (int it = 0; it < 4; ++it) {
            int i = it*16 + fr;
            bf16x8 q0 = ld8(&Qs[cur][i*64 + 8*(fq ^ (i & 7))]);
            bf16x8 q1 = ld8(&Qs[cur][i*64 + 8*((4 + fq) ^ (i & 7))]);
#pragma unroll
            for (int jt = 0; jt < 2; ++jt) {
                f32x4 s = MFMA16(kh[jt][0], q0, ((f32x4){0.f,0.f,0.f,0.f}));
                s = MFMA16(kh[jt][1], q1, s);
#pragma unroll
                for (int r = 0; r < 4; ++r)
                    accl[jt][r] += __builtin_amdgcn_exp2f(s[r]);
            }
        }
        __syncthreads();
    }
#pragma unroll
    for (int jt = 0; jt < 2; ++jt)
#pragma unroll
        for (int r = 0; r < 4; ++r) {
            accl[jt][r] += __shfl_xor(accl[jt][r], 1, 64);
            accl[jt][r] += __shfl_xor(accl[jt][r], 2, 64);
            accl[jt][r] += __shfl_xor(accl[jt][r], 4, 64);
            accl[jt][r] += __shfl_xor(accl[jt][r], 8, 64);
        }
    if (fr == 0) {
#pragma unroll
        for (int jt = 0; jt < 2; ++jt)
#pragma unroll
            for (int r = 0; r < 4; ++r)
                Lg[(size_t)bh*S_ + jw + jt*16 + fq*4 + r] =
                    -__log2f(accl[jt][r]);
    }
}

// ---------------------------------------------------------------------------
// Pass 2: X[i,:] = sum_j exp2(s_ij + Lg_j) * V[j,:]   (s pre-scaled by SC2)
// Lg folded into the score-MFMA C operand (C rows = j).  512 thr / 8 waves,
// 256 i, j-step 64, 1 barrier/step, K dbuf via gll16 pre-swizzled, V
// transpose-staged swizzled, wave-private P, setprio around PV MFMAs.
// 1D grid 512, bh = gid&63 -> all i-tiles of a (b,h) on one XCD.
// ---------------------------------------------------------------------------
__global__ __launch_bounds__(512, 4) void attn_pv(
    const __bf16* __restrict__ Q, const __bf16* __restrict__ K,
    const __bf16* __restrict__ V, const float* __restrict__ Lg,
    __bf16* __restrict__ X)
{
    __shared__ __align__(16) __bf16 Ks[2][64*64];   // 16 KB
    __shared__ __align__(16) __bf16 Vs[2][64*64];   // 16 KB
    __shared__ __align__(16) __bf16 Pl[8][32*64];   // 32 KB

    const int t = threadIdx.x, lane = t & 63, w = t >> 6;
    const int fr = lane & 15, fq = lane >> 4;
    const int gid = blockIdx.x;
    const int bh = gid & 63;
    const int iw = (gid >> 6)*256 + w*32;           // wave's i base
    const __bf16* Qb = Q + (size_t)bh*S_*DK_;
    const __bf16* Kb = K + (size_t)bh*S_*DK_;
    const __bf16* Vb = V + (size_t)bh*S_*DK_;
    const float*  Rb = Lg + (size_t)bh*S_;

    bf16x8 qf[2][2];
#pragma unroll
    for (int it = 0; it < 2; ++it)
#pragma unroll
        for (int kf = 0; kf < 2; ++kf)
            qf[it][kf] = ld8(&Qb[(size_t)(iw + it*16 + fr)*DK_ + kf*32 + fq*8]);

    const int dq = t & 15, jp = t >> 4;
    const int krow = t >> 3;
    const int kchk = (t & 7) ^ (krow & 7);

    f32x4 acc[2][4];
#pragma unroll
    for (int it = 0; it < 2; ++it)
#pragma unroll
        for (int dt = 0; dt < 4; ++dt) acc[it][dt] = (f32x4){0.f,0.f,0.f,0.f};

    gll16(&Kb[(size_t)krow*DK_ + kchk*8], &Ks[0][(t & ~63)*8]);
    __syncthreads();

    for (int jg = 0; jg < S_; jg += 64) {
        const int cur = (jg >> 6) & 1;

        bf16x4 v0 = *(const bf16x4*)&Vb[(size_t)(jg + 2*jp    )*DK_ + dq*4];
        bf16x4 v1 = *(const bf16x4*)&Vb[(size_t)(jg + 2*jp + 1)*DK_ + dq*4];
        f32x4 lg[4];
#pragma unroll
        for (int jt = 0; jt < 4; ++jt)
            lg[jt] = *(const f32x4*)&Rb[jg + jt*16 + fq*4];
        if (jg + 64 < S_)
            gll16(&Kb[(size_t)(jg + 64 + krow)*DK_ + kchk*8],
                  &Ks[cur ^ 1][(t & ~63)*8]);

#pragma unroll
        for (int jt = 0; jt < 4; ++jt) {
            const __bf16* kb = &Ks[cur][(jt*16 + fr)*64];
            bf16x8 af0 = ld8(kb + ((fq    ) ^ (fr & 7))*8);
            bf16x8 af1 = ld8(kb + ((fq + 4) ^ (fr & 7))*8);
#pragma unroll
            for (int it = 0; it < 2; ++it) {
                f32x4 s = MFMA16(af0, qf[it][0], lg[jt]);   // C-init = -log2 L
                s = MFMA16(af1, qf[it][1], s);
                bf16x4 pv;
#pragma unroll
                for (int r = 0; r < 4; ++r)
                    pv[r] = (__bf16)__builtin_amdgcn_exp2f(s[r]);
                int il = it*16 + fr;
                *(bf16x4*)&Pl[w][il*64 + (((jt*4 + fq) ^ (2*(fr & 7))))*4] = pv;
            }
        }

#pragma unroll
        for (int u = 0; u < 4; ++u) {
            int d = dq*4 + u;
            int f = (d ^ dq) & 7;
            *(bf16x2*)&Vs[cur][d*64 + (((jp >> 2) ^ f))*8 + (jp & 3)*2] =
                (bf16x2){ v0[u], v1[u] };
        }
        __syncthreads();

        __builtin_amdgcn_s_setprio(1);
#pragma unroll
        for (int kh = 0; kh < 2; ++kh) {
            bf16x8 pa0 = ld8(&Pl[w][(     fr)*64 + (((fq + 4*kh) ^ (fr & 7)))*8]);
            bf16x8 pa1 = ld8(&Pl[w][(16 + fr)*64 + (((fq + 4*kh) ^ (fr & 7)))*8]);
#pragma unroll
            for (int dt = 0; dt < 4; ++dt) {
                int d = dt*16 + fr;
                int f = (d ^ (d >> 2)) & 7;
                bf16x8 vb = ld8(&Vs[cur][d*64 + (((kh*4 + fq) ^ f))*8]);
                acc[0][dt] = MFMA16(pa0, vb, acc[0][dt]);
                acc[1][dt] = MFMA16(pa1, vb, acc[1][dt]);
            }
        }
        __builtin_amdgcn_s_setprio(0);
    }

    const int b = bh >> 4, h = bh & 15;
#pragma unroll
    for (int it = 0; it < 2; ++it)
#pragma unroll
        for (int dt = 0; dt < 4; ++dt)
#pragma unroll
            for (int r = 0; r < 4; ++r) {
                int i = iw + it*16 + fq*4 + r;
                X[((size_t)b*S_ + i)*D_ + h*DK_ + dt*16 + fr] =
                    (__bf16)acc[it][dt][r];
            }
}

// ---------------------------------------------------------------------------
// Host launcher
// ---------------------------------------------------------------------------
extern "C" void kernel_launch(void* const* d_in, const int* in_sizes, int n_in,
                              void* d_out, int out_size, void* d_ws, size_t ws_size,
                              hipStream_t stream)
{
    const float* query = (const float*)d_in[0];
    const float* key   = (const float*)d_in[1];
    const float* value = (const float*)d_in[2];
    const float* Wq = (const float*)d_in[3];  const float* bq = (const float*)d_in[4];
    const float* Wk = (const float*)d_in[5];  const float* bk = (const float*)d_in[6];
    const float* Wv = (const float*)d_in[7];  const float* bv = (const float*)d_in[8];
    const float* Wo = (const float*)d_in[9];  const float* bo = (const float*)d_in[10];

    char* ws = (char*)d_ws;
    char* dob = (char*)d_out;
    const size_t MiB = 1024 * 1024;
    __bf16* Qb = (__bf16*)(ws);              // [B,H,S,Dk] 16 MiB
    __bf16* Kb = (__bf16*)(ws + 16 * MiB);
    __bf16* Vb = (__bf16*)(ws + 32 * MiB);
    __bf16* Xb = (__bf16*)(ws + 48 * MiB);   // [B,S,D]
    float*  Lgb = (float*)d_out;             // 512 KiB @ d_out+0 (-log2 L)
    __bf16* Wt3 = (__bf16*)(dob + 1 * MiB);  // WtQ|WtK|WtV, 2 MiB each
    __bf16* WtO = (__bf16*)(ws);             // Qb region, reused after attn_pv

    // weights -> W^T bf16 (scratch in d_out; dead until final GEMM)
    wtrans3<<<dim3(16,16,3), 256, 0, stream>>>(Wq, Wk, Wv, Wt3);

    // batched Q/K/V projections (Q scaled by SC2_), 1536 blocks
    gemm_proj3<<<1536, 256, 0, stream>>>(query, key, value, Wt3,
                                         bq, bk, bv, Qb, Kb, Vb);

    colsum_rcp<<<1024, 256, 0, stream>>>(Qb, Kb, Lgb);

    attn_pv<<<512, 512, 0, stream>>>(Qb, Kb, Vb, Lgb, Xb);

    // Wo^T into Qb region (dead now); then final GEMM reads it from ws
    wtrans3<<<dim3(16,16,1), 256, 0, stream>>>(Wo, Wo, Wo, WtO);

    gemm128<1,0><<<512, 256, 0, stream>>>(Xb, WtO, bo, d_out, 1.0f);
}

// Round 8
// 381.917 us; speedup vs baseline: 1.0939x; 1.0012x over previous
//
#include <hip/hip_runtime.h>

// ---------------------------------------------------------------------------
// MultiHeadAttention (softmax over QUERY axis) — MI355X / gfx950, bf16 MFMA.
// B=4, S=2048, D=1024, H=16, Dk=64. Inputs/outputs fp32.
// attn[i,j] = exp(s_ij)/L_j, L_j = sum_i exp(s_ij)   (column softmax)
//
// ws (64 MiB): Qb@0 | Kb@16MiB | Vb@32MiB | Xb@48MiB  (bf16 [B,H,S,Dk]/[B,S,D])
// d_out scratch until final GEMM: Lg@+0 (512KiB) | WtQ/WtK/WtV bf16 @+1MiB.
// WtO transposed into ws@0 (Qb region, dead after attn_pv).
//
// ROUND-13: proj3 counters (r12) showed latency-bound-at-barrier: MfmaUtil 18,
// VALU 14, HBM 14, Occ 21% (2 blocks/CU, 64KB LDS).  Session A/B: R3
// (2-barrier BK32 16KB ~5blk) 48us/proj vs R5 (1-barrier dbuf BK64 64KB 2blk)
// 38us/proj.  (a) proj3 -> gemm_sb: 2-barrier BK=64 SINGLE-buffer 32KB ->
// ~5 blocks/CU: drain separation AND cross-block TLP (m114 overlap).
// (b) colsum: 2048 blocks, 16 j/wave -> 8 blocks/CU (was 4), doubles TLP
// hiding its per-step gll16 drains.  Final gemm / attn_pv / wtrans unchanged.
// ---------------------------------------------------------------------------

#define B_   4
#define S_   2048
#define D_   1024
#define H_   16
#define DK_  64
#define BH_  64
#define SC2_    0.18033688f   // 0.125 * log2(e), folded into Q projection

typedef __bf16 bf16x2 __attribute__((ext_vector_type(2)));
typedef __bf16 bf16x4 __attribute__((ext_vector_type(4)));
typedef __bf16 bf16x8 __attribute__((ext_vector_type(8)));
typedef float  f32x4  __attribute__((ext_vector_type(4)));
typedef unsigned int u32;

#define MFMA16(a,b,c) __builtin_amdgcn_mfma_f32_16x16x32_bf16((a),(b),(c),0,0,0)

__device__ __forceinline__ bf16x8 ld8(const __bf16* p){ return *(const bf16x8*)p; }

// async global->LDS, 16B per lane; LDS dest = wave-uniform base + lane*16
__device__ __forceinline__ void gll16(const __bf16* g, __bf16* l) {
    __builtin_amdgcn_global_load_lds(
        (const __attribute__((address_space(1))) u32*)g,
        (__attribute__((address_space(3))) u32*)l, 16, 0, 0);
}

// ---------------------------------------------------------------------------
// wtrans3: W [k][n] fp32 -> Wt [n][k] bf16, 3 matrices (blockIdx.z selects).
// 64x64 tile via LDS [64][80] (stride 160B: 16B-aligned, 2-lanes/bank).
// ---------------------------------------------------------------------------
__global__ __launch_bounds__(256) void wtrans3(
    const float* __restrict__ W0, const float* __restrict__ W1,
    const float* __restrict__ W2, __bf16* __restrict__ Wt)
{
    __shared__ __align__(16) __bf16 Ls[64][80];
    const int t = threadIdx.x;
    const int k0 = blockIdx.x * 64, n0 = blockIdx.y * 64, z = blockIdx.z;
    const float* W = (z == 0) ? W0 : ((z == 1) ? W1 : W2);
    __bf16* out = Wt + (size_t)z * D_ * D_;

#pragma unroll
    for (int p = 0; p < 4; ++p) {               // 1024 tasks: 64 k x 16 n-quads
        int id = p*256 + t;
        int k = id >> 4, nq = id & 15;
        f32x4 v = *(const f32x4*)&W[(size_t)(k0 + k)*D_ + n0 + nq*4];
#pragma unroll
        for (int u = 0; u < 4; ++u) Ls[nq*4 + u][k] = (__bf16)v[u];
    }
    __syncthreads();
#pragma unroll
    for (int p = 0; p < 2; ++p) {               // 512 tasks: 64 n x 8 chunks
        int id = p*256 + t;
        int n = id >> 3, c = id & 7;
        *(bf16x8*)&out[(size_t)(n0 + n)*D_ + k0 + c*8] =
            *(const bf16x8*)&Ls[n][c*8];
    }
}

// ---------------------------------------------------------------------------
// gemm_sb: 2-barrier SINGLE-buffered GEMM body for the fp32-A projections.
//   C[m][n] = (sum_k A[m][k]*Wt[n][k] + bias[n]) * scale, bf16 scatter out.
//   128x128 tile, BK=64, LDS 32 KB -> ~5 blocks/CU (TLP hides the barrier
//   drain; m114 mechanism).  4 waves (2x2, 64x64), 32 MFMA/iter, 16 iters.
//   Row stride 64 elem: chunk swizzle c^(row&7); B via gll16 (pre-swizzled
//   source), A fp32 reg-load + cvt + b128 write between the barriers.
// ---------------------------------------------------------------------------
__device__ __forceinline__ void gemm_sb(
    const float* __restrict__ Af, const __bf16* __restrict__ Wt,
    const float* __restrict__ bias, __bf16* __restrict__ C,
    float scale, int m0, int n0)
{
    __shared__ __align__(16) __bf16 As1[128*64];   // 16 KB
    __shared__ __align__(16) __bf16 Bs1[128*64];   // 16 KB

    const int t = threadIdx.x, lane = t & 63, w = t >> 6;
    const int wm = w >> 1, wn = w & 1;
    const int fr = lane & 15, fq = lane >> 4;

    f32x4 acc[4][4];
#pragma unroll
    for (int i = 0; i < 4; ++i)
#pragma unroll
        for (int j = 0; j < 4; ++j) acc[i][j] = (f32x4){0.f,0.f,0.f,0.f};

    for (int kk = 0; kk < D_; kk += 64) {
        __syncthreads();   // barrier 1: all waves done reading LDS
        // B tile: 128n x 64k, 1024 chunks, 4 gll16/thread (async, issue first)
#pragma unroll
        for (int p = 0; p < 4; ++p) {
            int idx = p*256 + t;
            int n = idx >> 3, l = (idx & 7) ^ (n & 7);
            gll16(&Wt[(size_t)(n0 + n)*D_ + kk + l*8],
                  &Bs1[(size_t)(p*256 + (t & ~63))*8]);
        }
        // A tile: fp32 load + cvt + swizzled b128 write
#pragma unroll
        for (int p = 0; p < 4; ++p) {
            int idx = p*256 + t;
            int row = idx >> 3, l = (idx & 7) ^ (row & 7);
            const float* ap = &Af[(size_t)(m0 + row)*D_ + kk + l*8];
            f32x4 x0 = *(const f32x4*)ap;
            f32x4 x1 = *(const f32x4*)(ap + 4);
            bf16x8 v = { (__bf16)x0[0], (__bf16)x0[1], (__bf16)x0[2],
                         (__bf16)x0[3], (__bf16)x1[0], (__bf16)x1[1],
                         (__bf16)x1[2], (__bf16)x1[3] };
            *(bf16x8*)&As1[(size_t)idx*8] = v;
        }
        __syncthreads();   // barrier 2: drains vm+lgkm, tiles ready

#pragma unroll
        for (int kh = 0; kh < 2; ++kh) {
            bf16x8 af[4], bfr[4];
#pragma unroll
            for (int mt = 0; mt < 4; ++mt) {
                int row = wm*64 + mt*16 + fr;
                af[mt] = ld8(&As1[row*64 + 8*((kh*4 + fq) ^ (row & 7))]);
            }
#pragma unroll
            for (int nt = 0; nt < 4; ++nt) {
                int n = wn*64 + nt*16 + fr;
                bfr[nt] = ld8(&Bs1[n*64 + 8*((kh*4 + fq) ^ (n & 7))]);
            }
#pragma unroll
            for (int mt = 0; mt < 4; ++mt)
#pragma unroll
                for (int nt = 0; nt < 4; ++nt)
                    acc[mt][nt] = MFMA16(af[mt], bfr[nt], acc[mt][nt]);
        }
    }

#pragma unroll
    for (int mt = 0; mt < 4; ++mt)
#pragma unroll
        for (int nt = 0; nt < 4; ++nt) {
            int colg = n0 + wn*64 + nt*16 + fr;
            float bv = bias[colg];
#pragma unroll
            for (int r = 0; r < 4; ++r) {
                int rowg = m0 + wm*64 + mt*16 + fq*4 + r;
                float o = (acc[mt][nt][r] + bv) * scale;
                int b = rowg >> 11, sp = rowg & (S_-1);
                int h = colg >> 6, dk = colg & 63;
                C[(((size_t)(b*H_ + h))*S_ + sp)*DK_ + dk] = (__bf16)o;
            }
        }
}

// batched Q/K/V projection: 1536 blocks, z = gid>>9 selects the sub-GEMM.
// (gid&511) keeps the XCD m-grouping (512 % 64 == 0).
__global__ __launch_bounds__(256) void gemm_proj3(
    const float* __restrict__ q, const float* __restrict__ k,
    const float* __restrict__ v, const __bf16* __restrict__ Wt3,
    const float* __restrict__ bq, const float* __restrict__ bk,
    const float* __restrict__ bv,
    __bf16* __restrict__ Qb, __bf16* __restrict__ Kb, __bf16* __restrict__ Vb)
{
    const int gid = blockIdx.x;
    const int z = gid >> 9, inner = gid & 511;
    const float*  A    = (z == 0) ? q  : ((z == 1) ? k  : v);
    const __bf16* Wt   = Wt3 + (size_t)z * D_ * D_;
    const float*  bias = (z == 0) ? bq : ((z == 1) ? bk : bv);
    __bf16*       C    = (z == 0) ? Qb : ((z == 1) ? Kb : Vb);
    const float scale  = (z == 0) ? SC2_ : 1.0f;
    gemm_sb(A, Wt, bias, C, scale, (inner & 63) * 128, (inner >> 6) * 128);
}

// ---------------------------------------------------------------------------
// GEMM body (round-5 measured-best 1-barrier dbuf BK=64) — final GEMM only.
//   ABF16=1 path: all staging via gll16.  MODE 0: C fp32 [8192][1024].
// ---------------------------------------------------------------------------
template<int ABF16, int MODE>
__device__ __forceinline__ void gemm_body(
    const void* __restrict__ Ap, const __bf16* __restrict__ Wt,
    const float* __restrict__ bias, void* __restrict__ C,
    float scale, int m0, int n0)
{
    __shared__ __align__(16) __bf16 As[2][128*64];   // 16 KB x2
    __shared__ __align__(16) __bf16 Bs[2][128*64];   // 16 KB x2

    const int t = threadIdx.x, lane = t & 63, w = t >> 6;
    const int wm = w >> 1, wn = w & 1;
    const int fr = lane & 15, fq = lane >> 4;

    const __bf16* Ab = (const __bf16*)Ap;
    const float*  Af = (const float*)Ap;

    f32x4 acc[4][4];
#pragma unroll
    for (int i = 0; i < 4; ++i)
#pragma unroll
        for (int j = 0; j < 4; ++j) acc[i][j] = (f32x4){0.f,0.f,0.f,0.f};

#define STAGE_B(kk, bsel)                                                     \
    _Pragma("unroll")                                                         \
    for (int p = 0; p < 4; ++p) {                                             \
        int idx = p*256 + t;                                                  \
        int n = idx >> 3, l = (idx & 7) ^ (n & 7);                            \
        gll16(&Wt[(size_t)(n0 + n)*D_ + (kk) + l*8],                          \
              &Bs[bsel][(size_t)(p*256 + (t & ~63))*8]);                      \
    }

#define STAGE_A_BF(kk, bsel)                                                  \
    _Pragma("unroll")                                                         \
    for (int p = 0; p < 4; ++p) {                                             \
        int idx = p*256 + t;                                                  \
        int row = idx >> 3, l = (idx & 7) ^ (row & 7);                        \
        gll16(&Ab[(size_t)(m0 + row)*D_ + (kk) + l*8],                        \
              &As[bsel][(size_t)(p*256 + (t & ~63))*8]);                      \
    }

#define LOAD_A_F32(kk, xa)                                                    \
    _Pragma("unroll")                                                         \
    for (int p = 0; p < 4; ++p) {                                             \
        int idx = p*256 + t;                                                  \
        int row = idx >> 3, l = (idx & 7) ^ (row & 7);                        \
        const float* ap = &Af[(size_t)(m0 + row)*D_ + (kk) + l*8];            \
        xa[2*p]   = *(const f32x4*)ap;                                        \
        xa[2*p+1] = *(const f32x4*)(ap + 4);                                  \
    }

#define WRITE_A_F32(xa, bsel)                                                 \
    _Pragma("unroll")                                                         \
    for (int p = 0; p < 4; ++p) {                                             \
        f32x4 x0 = xa[2*p], x1 = xa[2*p+1];                                   \
        bf16x8 v = { (__bf16)x0[0], (__bf16)x0[1], (__bf16)x0[2],             \
                     (__bf16)x0[3], (__bf16)x1[0], (__bf16)x1[1],             \
                     (__bf16)x1[2], (__bf16)x1[3] };                          \
        *(bf16x8*)&As[bsel][(size_t)(p*256 + t)*8] = v;                       \
    }

    if (ABF16) {
        STAGE_A_BF(0, 0)
    } else {
        f32x4 xa[8];
        LOAD_A_F32(0, xa)
        WRITE_A_F32(xa, 0)
    }
    STAGE_B(0, 0)
    __syncthreads();

    for (int kk = 0; kk < D_; kk += 64) {
        const int cur = (kk >> 6) & 1;
        const bool more = (kk + 64) < D_;

        f32x4 xa[8];
        if (more) {
            if (ABF16) {
                STAGE_A_BF(kk + 64, cur ^ 1)
            } else {
                LOAD_A_F32(kk + 64, xa)
            }
            STAGE_B(kk + 64, cur ^ 1)
        }

#pragma unroll
        for (int kh = 0; kh < 2; ++kh) {
            bf16x8 af[4], bfr[4];
#pragma unroll
            for (int mt = 0; mt < 4; ++mt) {
                int row = wm*64 + mt*16 + fr;
                af[mt] = ld8(&As[cur][row*64 + 8*((kh*4 + fq) ^ (row & 7))]);
            }
#pragma unroll
            for (int nt = 0; nt < 4; ++nt) {
                int n = wn*64 + nt*16 + fr;
                bfr[nt] = ld8(&Bs[cur][n*64 + 8*((kh*4 + fq) ^ (n & 7))]);
            }
#pragma unroll
            for (int mt = 0; mt < 4; ++mt)
#pragma unroll
                for (int nt = 0; nt < 4; ++nt)
                    acc[mt][nt] = MFMA16(af[mt], bfr[nt], acc[mt][nt]);
        }

        if (more && !ABF16) {
            WRITE_A_F32(xa, cur ^ 1)
        }
        __syncthreads();
    }
#undef STAGE_B
#undef STAGE_A_BF
#undef LOAD_A_F32
#undef WRITE_A_F32

#pragma unroll
    for (int mt = 0; mt < 4; ++mt)
#pragma unroll
        for (int nt = 0; nt < 4; ++nt) {
            int colg = n0 + wn*64 + nt*16 + fr;
            float bv = bias[colg];
#pragma unroll
            for (int r = 0; r < 4; ++r) {
                int rowg = m0 + wm*64 + mt*16 + fq*4 + r;
                float o = (acc[mt][nt][r] + bv) * scale;
                if (MODE == 0) {
                    ((float*)C)[(size_t)rowg*D_ + colg] = o;
                } else {
                    int b = rowg >> 11, sp = rowg & (S_-1);
                    int h = colg >> 6, dk = colg & 63;
                    ((__bf16*)C)[(((size_t)(b*H_ + h))*S_ + sp)*DK_ + dk] = (__bf16)o;
                }
            }
        }
}

// single-GEMM wrapper (final output GEMM); 1D grid 512: m = gid&63
template<int ABF16, int MODE>
__global__ __launch_bounds__(256) void gemm128(
    const void* __restrict__ Ap, const __bf16* __restrict__ Wt,
    const float* __restrict__ bias, void* __restrict__ C, float scale)
{
    const int gid = blockIdx.x;
    gemm_body<ABF16, MODE>(Ap, Wt, bias, C, scale,
                           (gid & 63) * 128, ((gid >> 6) & 7) * 128);
}

// ---------------------------------------------------------------------------
// Column-softmax log-sums: Lg[bh][j] = -log2( sum_i exp2(s_ij) ).
//   2048 blocks (1D, bh = gid&63 -> XCD-local Q), 4 waves x 16 j each:
//   16 KB LDS + ~50 VGPR -> 8 blocks/CU, 32 waves/CU (was 4 blocks) to hide
//   the per-step gll16 drain.  K-frags loop-invariant in regs; i-step 64,
//   Qs dbuf via gll16 prefetch (pre-swizzled source), ONE barrier per step.
// ---------------------------------------------------------------------------
__global__ __launch_bounds__(256) void colsum_rcp(
    const __bf16* __restrict__ Q, const __bf16* __restrict__ K,
    float* __restrict__ Lg)
{
    __shared__ __align__(16) __bf16 Qs[2][64*64];   // 16 KB
    const int t = threadIdx.x, lane = t & 63, w = t >> 6;
    const int fr = lane & 15, fq = lane >> 4;
    const int gid = blockIdx.x;
    const int bh = gid & 63;
    const int jw = (gid >> 6)*64 + w*16;            // wave's 16 j
    const __bf16* Qb = Q + (size_t)bh*S_*DK_;
    const __bf16* Kb = K + (size_t)bh*S_*DK_;

    bf16x8 kh0, kh1;
    {
        const __bf16* kr = &Kb[(size_t)(jw + fr)*DK_];
        kh0 = ld8(kr + fq*8);
        kh1 = ld8(kr + 32 + fq*8);
    }

    float accl[4] = {};

    // prologue: stage Qs[0] (rows 0..63), pre-swizzled source
#pragma unroll
    for (int p = 0; p < 2; ++p) {
        int c = p*256 + t;
        int i = c >> 3, l = (c & 7) ^ (i & 7);
        gll16(&Qb[(size_t)i*DK_ + l*8], &Qs[0][(size_t)(p*256 + (t & ~63))*8]);
    }
    __syncthreads();

    for (int i0 = 0; i0 < S_; i0 += 64) {
        const int cur = (i0 >> 6) & 1;
        if (i0 + 64 < S_) {
#pragma unroll
            for (int p = 0; p < 2; ++p) {
                int c = p*256 + t;
                int i = c >> 3, l = (c & 7) ^ (i & 7);
                gll16(&Qb[(size_t)(i0 + 64 + i)*DK_ + l*8],
                      &Qs[cur ^ 1][(size_t)(p*256 + (t & ~63))*8]);
            }
        }
#pragma unroll
        for (int it = 0; it < 4; ++it) {
            int i = it*16 + fr;
            bf16x8 q0 = ld8(&Qs[cur][i*64 + 8*(fq ^ (i & 7))]);
            bf16x8 q1 = ld8(&Qs[cur][i*64 + 8*((4 + fq) ^ (i & 7))]);
            f32x4 s = MFMA16(kh0, q0, ((f32x4){0.f,0.f,0.f,0.f}));
            s = MFMA16(kh1, q1, s);
#pragma unroll
            for (int r = 0; r < 4; ++r)
                accl[r] += __builtin_amdgcn_exp2f(s[r]);
        }
        __syncthreads();
    }
#pragma unroll
    for (int r = 0; r < 4; ++r) {
        accl[r] += __shfl_xor(accl[r], 1, 64);
        accl[r] += __shfl_xor(accl[r], 2, 64);
        accl[r] += __shfl_xor(accl[r], 4, 64);
        accl[r] += __shfl_xor(accl[r], 8, 64);
    }
    if (fr == 0) {
#pragma unroll
        for (int r = 0; r < 4; ++r)
            Lg[(size_t)bh*S_ + jw + fq*4 + r] = -__log2f(accl[r]);
    }
}

// ---------------------------------------------------------------------------
// Pass 2: X[i,:] = sum_j exp2(s_ij + Lg_j) * V[j,:]   (s pre-scaled by SC2)
// Lg folded into the score-MFMA C operand (C rows = j).  512 thr / 8 waves,
// 256 i, j-step 64, 1 barrier/step, K dbuf via gll16 pre-swizzled, V
// transpose-staged swizzled, wave-private P, setprio around PV MFMAs.
// 1D grid 512, bh = gid&63 -> all i-tiles of a (b,h) on one XCD.
// ---------------------------------------------------------------------------
__global__ __launch_bounds__(512, 4) void attn_pv(
    const __bf16* __restrict__ Q, const __bf16* __restrict__ K,
    const __bf16* __restrict__ V, const float* __restrict__ Lg,
    __bf16* __restrict__ X)
{
    __shared__ __align__(16) __bf16 Ks[2][64*64];   // 16 KB
    __shared__ __align__(16) __bf16 Vs[2][64*64];   // 16 KB
    __shared__ __align__(16) __bf16 Pl[8][32*64];   // 32 KB

    const int t = threadIdx.x, lane = t & 63, w = t >> 6;
    const int fr = lane & 15, fq = lane >> 4;
    const int gid = blockIdx.x;
    const int bh = gid & 63;
    const int iw = (gid >> 6)*256 + w*32;           // wave's i base
    const __bf16* Qb = Q + (size_t)bh*S_*DK_;
    const __bf16* Kb = K + (size_t)bh*S_*DK_;
    const __bf16* Vb = V + (size_t)bh*S_*DK_;
    const float*  Rb = Lg + (size_t)bh*S_;

    bf16x8 qf[2][2];
#pragma unroll
    for (int it = 0; it < 2; ++it)
#pragma unroll
        for (int kf = 0; kf < 2; ++kf)
            qf[it][kf] = ld8(&Qb[(size_t)(iw + it*16 + fr)*DK_ + kf*32 + fq*8]);

    const int dq = t & 15, jp = t >> 4;
    const int krow = t >> 3;
    const int kchk = (t & 7) ^ (krow & 7);

    f32x4 acc[2][4];
#pragma unroll
    for (int it = 0; it < 2; ++it)
#pragma unroll
        for (int dt = 0; dt < 4; ++dt) acc[it][dt] = (f32x4){0.f,0.f,0.f,0.f};

    gll16(&Kb[(size_t)krow*DK_ + kchk*8], &Ks[0][(t & ~63)*8]);
    __syncthreads();

    for (int jg = 0; jg < S_; jg += 64) {
        const int cur = (jg >> 6) & 1;

        bf16x4 v0 = *(const bf16x4*)&Vb[(size_t)(jg + 2*jp    )*DK_ + dq*4];
        bf16x4 v1 = *(const bf16x4*)&Vb[(size_t)(jg + 2*jp + 1)*DK_ + dq*4];
        f32x4 lg[4];
#pragma unroll
        for (int jt = 0; jt < 4; ++jt)
            lg[jt] = *(const f32x4*)&Rb[jg + jt*16 + fq*4];
        if (jg + 64 < S_)
            gll16(&Kb[(size_t)(jg + 64 + krow)*DK_ + kchk*8],
                  &Ks[cur ^ 1][(t & ~63)*8]);

#pragma unroll
        for (int jt = 0; jt < 4; ++jt) {
            const __bf16* kb = &Ks[cur][(jt*16 + fr)*64];
            bf16x8 af0 = ld8(kb + ((fq    ) ^ (fr & 7))*8);
            bf16x8 af1 = ld8(kb + ((fq + 4) ^ (fr & 7))*8);
#pragma unroll
            for (int it = 0; it < 2; ++it) {
                f32x4 s = MFMA16(af0, qf[it][0], lg[jt]);   // C-init = -log2 L
                s = MFMA16(af1, qf[it][1], s);
                bf16x4 pv;
#pragma unroll
                for (int r = 0; r < 4; ++r)
                    pv[r] = (__bf16)__builtin_amdgcn_exp2f(s[r]);
                int il = it*16 + fr;
                *(bf16x4*)&Pl[w][il*64 + (((jt*4 + fq) ^ (2*(fr & 7))))*4] = pv;
            }
        }

#pragma unroll
        for (int u = 0; u < 4; ++u) {
            int d = dq*4 + u;
            int f = (d ^ dq) & 7;
            *(bf16x2*)&Vs[cur][d*64 + (((jp >> 2) ^ f))*8 + (jp & 3)*2] =
                (bf16x2){ v0[u], v1[u] };
        }
        __syncthreads();

        __builtin_amdgcn_s_setprio(1);
#pragma unroll
        for (int kh = 0; kh < 2; ++kh) {
            bf16x8 pa0 = ld8(&Pl[w][(     fr)*64 + (((fq + 4*kh) ^ (fr & 7)))*8]);
            bf16x8 pa1 = ld8(&Pl[w][(16 + fr)*64 + (((fq + 4*kh) ^ (fr & 7)))*8]);
#pragma unroll
            for (int dt = 0; dt < 4; ++dt) {
                int d = dt*16 + fr;
                int f = (d ^ (d >> 2)) & 7;
                bf16x8 vb = ld8(&Vs[cur][d*64 + (((kh*4 + fq) ^ f))*8]);
                acc[0][dt] = MFMA16(pa0, vb, acc[0][dt]);
                acc[1][dt] = MFMA16(pa1, vb, acc[1][dt]);
            }
        }
        __builtin_amdgcn_s_setprio(0);
    }

    const int b = bh >> 4, h = bh & 15;
#pragma unroll
    for (int it = 0; it < 2; ++it)
#pragma unroll
        for (int dt = 0; dt < 4; ++dt)
#pragma unroll
            for (int r = 0; r < 4; ++r) {
                int i = iw + it*16 + fq*4 + r;
                X[((size_t)b*S_ + i)*D_ + h*DK_ + dt*16 + fr] =
                    (__bf16)acc[it][dt][r];
            }
}

// ---------------------------------------------------------------------------
// Host launcher
// ---------------------------------------------------------------------------
extern "C" void kernel_launch(void* const* d_in, const int* in_sizes, int n_in,
                              void* d_out, int out_size, void* d_ws, size_t ws_size,
                              hipStream_t stream)
{
    const float* query = (const float*)d_in[0];
    const float* key   = (const float*)d_in[1];
    const float* value = (const float*)d_in[2];
    const float* Wq = (const float*)d_in[3];  const float* bq = (const float*)d_in[4];
    const float* Wk = (const float*)d_in[5];  const float* bk = (const float*)d_in[6];
    const float* Wv = (const float*)d_in[7];  const float* bv = (const float*)d_in[8];
    const float* Wo = (const float*)d_in[9];  const float* bo = (const float*)d_in[10];

    char* ws = (char*)d_ws;
    char* dob = (char*)d_out;
    const size_t MiB = 1024 * 1024;
    __bf16* Qb = (__bf16*)(ws);              // [B,H,S,Dk] 16 MiB
    __bf16* Kb = (__bf16*)(ws + 16 * MiB);
    __bf16* Vb = (__bf16*)(ws + 32 * MiB);
    __bf16* Xb = (__bf16*)(ws + 48 * MiB);   // [B,S,D]
    float*  Lgb = (float*)d_out;             // 512 KiB @ d_out+0 (-log2 L)
    __bf16* Wt3 = (__bf16*)(dob + 1 * MiB);  // WtQ|WtK|WtV, 2 MiB each
    __bf16* WtO = (__bf16*)(ws);             // Qb region, reused after attn_pv

    // weights -> W^T bf16 (scratch in d_out; dead until final GEMM)
    wtrans3<<<dim3(16,16,3), 256, 0, stream>>>(Wq, Wk, Wv, Wt3);

    // batched Q/K/V projections (Q scaled by SC2_), 1536 blocks, gemm_sb body
    gemm_proj3<<<1536, 256, 0, stream>>>(query, key, value, Wt3,
                                         bq, bk, bv, Qb, Kb, Vb);

    colsum_rcp<<<2048, 256, 0, stream>>>(Qb, Kb, Lgb);

    attn_pv<<<512, 512, 0, stream>>>(Qb, Kb, Vb, Lgb, Xb);

    // Wo^T into Qb region (dead now); then final GEMM reads it from ws
    wtrans3<<<dim3(16,16,1), 256, 0, stream>>>(Wo, Wo, Wo, WtO);

    gemm128<1,0><<<512, 256, 0, stream>>>(Xb, WtO, bo, d_out, 1.0f);
}